// Round 14
// baseline (379.548 us; speedup 1.0000x reference)
//
#include <hip/hip_runtime.h>
#include <stdint.h>

#define NR 8192
#define DE 1024
#define DC 512
#define BIGF 9999999.0f
#define MARG 0.3f
#define NEGI -3.0e38f
#define POSI 3.0e38f
#define CAP 64   // max class size served by posmat fast path; larger falls back (never for this input)

typedef __attribute__((ext_vector_type(8))) short bf16x8;
typedef __attribute__((ext_vector_type(4))) float f32x4;

typedef __attribute__((address_space(3))) unsigned int lds_u32;
typedef const __attribute__((address_space(1))) unsigned int glb_u32;

static __device__ __forceinline__ void ld_g2l16(const void* g, void* l) {
    __builtin_amdgcn_global_load_lds((glb_u32*)g, (lds_u32*)l, 16, 0, 0);
}

static __device__ __forceinline__ unsigned short f2bf(float x) {
    unsigned u = __float_as_uint(x);
    unsigned r = u + 0x7FFFu + ((u >> 16) & 1u);
    return (unsigned short)(r >> 16);
}

static __device__ __forceinline__ float b2f(short u) {
    return __uint_as_float(((unsigned)(unsigned short)u) << 16);
}

// ---------------- K1: emb -> bf16, sq, class histogram, mnA init ----------------
__global__ __launch_bounds__(256) void k_prep_emb(const float* __restrict__ emb,
                                                  const int* __restrict__ label,
                                                  short* __restrict__ embb,
                                                  float* __restrict__ sq,
                                                  int* __restrict__ cnt,
                                                  unsigned* __restrict__ mnA) {
    int w = threadIdx.x >> 6, lane = threadIdx.x & 63;
    int row = blockIdx.x * 4 + w;
    const float4* src = (const float4*)(emb + (size_t)row * DE);
    ushort4* dst = (ushort4*)(embb + (size_t)row * DE);
    float s = 0.f;
#pragma unroll
    for (int c = 0; c < 4; ++c) {
        float4 v = src[c * 64 + lane];
        s += v.x * v.x + v.y * v.y + v.z * v.z + v.w * v.w;
        ushort4 b;
        b.x = f2bf(v.x); b.y = f2bf(v.y); b.z = f2bf(v.z); b.w = f2bf(v.w);
        dst[c * 64 + lane] = b;
    }
    for (int m = 1; m < 64; m <<= 1) s += __shfl_xor(s, m);
    if (lane == 0) {
        sq[row] = s;
        atomicAdd(&cnt[label[row]], 1);
        mnA[row] = 0xFFFFFFFFu;          // +inf bits for positive-float atomicMin
    }
}

// ---------------- K3: scan (in-block, redundant) + scatter rows into class lists ----------------
__global__ __launch_bounds__(256) void k_fill(const int* __restrict__ cnt,
                                              const int* __restrict__ label,
                                              int* __restrict__ clsOff,
                                              int* __restrict__ fill,
                                              int* __restrict__ list,
                                              int* __restrict__ mIdx) {
    __shared__ int s[512];
    int t = threadIdx.x;
    s[t] = cnt[t];
    s[t + 256] = cnt[t + 256];
    __syncthreads();
    for (int d = 1; d < 512; d <<= 1) {
        int v0 = (t >= d) ? s[t - d] : 0;
        int v1 = s[t + 256 - d];
        __syncthreads();
        s[t] += v0;
        s[t + 256] += v1;
        __syncthreads();
    }
    if (blockIdx.x == 0) {
        clsOff[t] = s[t] - cnt[t];
        clsOff[t + 256] = s[t + 256] - cnt[t + 256];
    }
    int i = blockIdx.x * 256 + t;
    int l = label[i];
    int p = atomicAdd(&fill[l], 1);
    list[s[l] - cnt[l] + p] = i;
    mIdx[i] = p;
}

// ---------------- K4: symmetric GEMM + min-negative reduction + same-class d2 export ----------------
// R10 winner loop unchanged. ROUND-14 DELTA (epilogue only): mIdx preloaded into registers
// (mIj[4] with the column loads, mIi[4] with each mi-group's row loads) so the rare
// lbi==lbj branch body is compare + 2 fire-and-forget stores -- no dependent L2 loads.
// R13's +11us epilogue regression matched ~8 divergent excursions x ~400cy of mIdx-load
// stall per wave; this removes the load from the excursion.
__global__ __launch_bounds__(256, 3) void k_main(const short* __restrict__ embb,
                                                 const float* __restrict__ sq,
                                                 const int* __restrict__ label,
                                                 const int* __restrict__ mIdx,
                                                 unsigned* __restrict__ mnA,
                                                 float* __restrict__ posmat) {
    // decode b -> (r, c), r <= c < 64: off(r) = 64r - r(r-1)/2 ; c = r + (b - off(r))
    const int b = blockIdx.x;
    int r = (int)((129.0f - sqrtf(16641.0f - 8.0f * (float)b)) * 0.5f);
    if (r < 0) r = 0;
    if (r > 63) r = 63;
    while (r > 0 && 64 * r - (r * (r - 1)) / 2 > b) --r;
    while (64 * (r + 1) - ((r + 1) * r) / 2 <= b) ++r;
    const int c = r + (b - (64 * r - (r * (r - 1)) / 2));
    const int i0 = r * 128, j0 = c * 128;

    __shared__ __align__(16) short As[128 * 64];   // 16KB
    __shared__ __align__(16) short Bs[128 * 64];   // 16KB

    const int tid = threadIdx.x;
    const int lane = tid & 63;
    const int w = tid >> 6;
    const int wr = w >> 1, wc = w & 1;       // 2x2 wave grid over the 128x128 panel
    const int q = lane >> 4, l15 = lane & 15;

    // staging source: row offset t>>3, source chunk g = slot ^ (row&7)
    const int g = (tid & 7) ^ ((tid >> 3) & 7);
    const short* gA = embb + (size_t)(i0 + (tid >> 3)) * DE + g * 8;
    const short* gB = embb + (size_t)(j0 + (tid >> 3)) * DE + g * 8;

    const int swz = l15 & 7;                 // read-side row swizzle key

    auto stage = [&](int koff) {
#pragma unroll
        for (int n = 0; n < 4; ++n) {
            ld_g2l16(gA + (size_t)n * 32 * DE + koff, &As[n * 2048 + tid * 8]);
            ld_g2l16(gB + (size_t)n * 32 * DE + koff, &Bs[n * 2048 + tid * 8]);
        }
    };

    stage(0);   // prefetch ks=0

    f32x4 acc[4][4];
#pragma unroll
    for (int mi = 0; mi < 4; ++mi)
#pragma unroll
        for (int ni = 0; ni < 4; ++ni) acc[mi][ni] = (f32x4){0.f, 0.f, 0.f, 0.f};

    for (int ks = 0; ks < 16; ++ks) {
        __syncthreads();          // staging visible (vmcnt drain)
        bf16x8 af[2][4], bfr[2][4];
#pragma unroll
        for (int kk = 0; kk < 2; ++kk) {
            const int kc = ((kk * 4 + q) ^ swz) * 8;
#pragma unroll
            for (int mi = 0; mi < 4; ++mi)
                af[kk][mi] = *(const bf16x8*)&As[(wr * 64 + mi * 16 + l15) * 64 + kc];
#pragma unroll
            for (int ni = 0; ni < 4; ++ni)
                bfr[kk][ni] = *(const bf16x8*)&Bs[(wc * 64 + ni * 16 + l15) * 64 + kc];
        }
#pragma unroll
        for (int kk = 0; kk < 2; ++kk)
#pragma unroll
            for (int mi = 0; mi < 4; ++mi)
#pragma unroll
                for (int ni = 0; ni < 4; ++ni)
                    acc[mi][ni] = __builtin_amdgcn_mfma_f32_16x16x32_bf16(af[kk][mi], bfr[kk][ni], acc[mi][ni], 0, 0, 0);
        __syncthreads();          // all reads done before next staging writes
        if (ks < 15) stage((ks + 1) * 64);
    }

    // ---- epilogue: masked d2 -> row/col min + same-class d2 -> posmat ----
    const int rb = i0 + wr * 64, cb = j0 + wc * 64;
    float sqj[4]; int lbj[4], mIj[4]; float cmn[4];
#pragma unroll
    for (int ni = 0; ni < 4; ++ni) {
        int cg = cb + ni * 16 + l15;
        sqj[ni] = sq[cg]; lbj[ni] = label[cg]; mIj[ni] = mIdx[cg]; cmn[ni] = POSI;
    }
#pragma unroll
    for (int mi = 0; mi < 4; ++mi) {
        float rm[4] = {POSI, POSI, POSI, POSI};
        float sqi[4]; int lbi[4], mIi[4];
#pragma unroll
        for (int rr = 0; rr < 4; ++rr) {
            int rg = rb + mi * 16 + q * 4 + rr;
            sqi[rr] = sq[rg]; lbi[rr] = label[rg]; mIi[rr] = mIdx[rg];
        }
#pragma unroll
        for (int ni = 0; ni < 4; ++ni)
#pragma unroll
            for (int rr = 0; rr < 4; ++rr) {
                float d2 = fmaf(-2.0f, acc[mi][ni][rr], sqi[rr] + sqj[ni]);
                d2 = fmaxf(d2, 1e-12f);
                if (lbi[rr] == lbj[ni]) {
                    int a = mIi[rr], bb = mIj[ni];
                    if (a < CAP && bb < CAP) {
                        float* pm = posmat + (size_t)lbi[rr] * CAP * CAP;
                        pm[a * CAP + bb] = d2;
                        pm[bb * CAP + a] = d2;
                    }
                }
                float dn = (lbi[rr] == lbj[ni]) ? POSI : d2;
                rm[rr] = fminf(rm[rr], dn);
                cmn[ni] = fminf(cmn[ni], dn);
            }
#pragma unroll
        for (int rr = 0; rr < 4; ++rr) {
            float v = rm[rr];
            v = fminf(v, __shfl_xor(v, 1));
            v = fminf(v, __shfl_xor(v, 2));
            v = fminf(v, __shfl_xor(v, 4));
            v = fminf(v, __shfl_xor(v, 8));
            if (l15 == 0) atomicMin(&mnA[rb + mi * 16 + q * 4 + rr], __float_as_uint(v));
        }
    }
#pragma unroll
    for (int ni = 0; ni < 4; ++ni) {
        float v = cmn[ni];
        v = fminf(v, __shfl_xor(v, 16));
        v = fminf(v, __shfl_xor(v, 32));
        if (q == 0) atomicMin(&mnA[cb + ni * 16 + l15], __float_as_uint(v));
    }
}

// ---------------- K5: positives (top-2) from posmat + alphas + FUSED final reduction ----------------
// ROUND-14: k_final folded in via last-block-done. Every block: device fence -> thread 0
// bumps ctr; the block that sees gridDim-1 re-fences (acquire) and runs the final loss
// reduction (~3us). No divergent returns -- all blocks reach the atomic. Counter zeroed
// by the host-side memset. Cross-XCD safe: __threadfence + atomicAdd are device-scope (G16).
__global__ __launch_bounds__(256) void k_pos(const short* __restrict__ embb,
                                             const float* __restrict__ sq,
                                             const float* __restrict__ clot,
                                             const int* __restrict__ label,
                                             const int* __restrict__ cnt,
                                             const int* __restrict__ clsOff,
                                             const int* __restrict__ clsList,
                                             const int* __restrict__ mIdx,
                                             const float* __restrict__ posmat,
                                             const unsigned* __restrict__ mnA,
                                             float* __restrict__ ap1, float* __restrict__ ap2,
                                             float* __restrict__ an,
                                             float* __restrict__ alpha1, float* __restrict__ alpha2,
                                             int* __restrict__ ctr,
                                             float* __restrict__ out) {
    int wid = threadIdx.x >> 6, lane = threadIdx.x & 63;
    int row = blockIdx.x * 4 + wid;
    int lb = label[row];
    int cc = cnt[lb], off = clsOff[lb];
    float sqiv = sq[row];

    float v1 = NEGI, v2 = NEGI;
    int i1 = 0, i2 = 0;
    auto upd = [&](float d2, int j) {
        bool t1 = (d2 > v1) || (d2 == v1 && j < i1);
        bool t2 = (d2 > v2) || (d2 == v2 && j < i2);
        v2 = t1 ? v1 : (t2 ? d2 : v2);
        i2 = t1 ? i1 : (t2 ? j : i2);
        v1 = t1 ? d2 : v1;
        i1 = t1 ? j : i1;
    };

    if (cc <= CAP) {
        const int self = mIdx[row];
        if (lane < cc) {
            float d2 = (lane == self) ? 1e-12f
                                      : posmat[((size_t)lb * CAP + self) * CAP + lane];
            upd(d2, clsList[off + lane]);
        }
        for (int d = 1; d < 64; d <<= 1) {
            float o1 = __shfl_xor(v1, d), o2 = __shfl_xor(v2, d);
            int oi1 = __shfl_xor(i1, d), oi2 = __shfl_xor(i2, d);
            upd(o1, oi1);
            upd(o2, oi2);
        }
    } else {
        // fallback: serial classmate dots (wave-parallel over D) -- never for this input
        const bf16x8* rp = (const bf16x8*)(embb + (size_t)row * DE + lane * 16);
        bf16x8 ra = rp[0], rb = rp[1];
        float rf[16];
#pragma unroll
        for (int t = 0; t < 8; ++t) { rf[t] = b2f(ra[t]); rf[8 + t] = b2f(rb[t]); }
        for (int m = 0; m < cc; ++m) {
            int j = clsList[off + m];
            float d2;
            if (j == row) {
                d2 = 1e-12f;
            } else {
                const bf16x8* jp = (const bf16x8*)(embb + (size_t)j * DE + lane * 16);
                bf16x8 ja = jp[0], jb = jp[1];
                float s = 0.f;
#pragma unroll
                for (int t = 0; t < 8; ++t) s = fmaf(rf[t], b2f(ja[t]), s);
#pragma unroll
                for (int t = 0; t < 8; ++t) s = fmaf(rf[8 + t], b2f(jb[t]), s);
                for (int mm = 1; mm < 64; mm <<= 1) s += __shfl_xor(s, mm);
                d2 = fmaxf(fmaf(-2.0f, s, sqiv + sq[j]), 1e-12f);
            }
            upd(d2, j);
        }
    }

    float a1 = sqrtf(v1);
    int j1 = i1;
    float a2v; int j2;
    if (cc >= 2) {
        a2v = sqrtf(v2);
        j2 = i2;
    } else {
        // singleton class: ref falls back to best (max-dist) negative - BIG
        float kv = NEGI; int ki = 0;
        for (int cr = lane; cr < NR; cr += 64) {
            if (label[cr] == lb) continue;
            float s = 0.f;
            const short* crow = embb + (size_t)cr * DE;
            const short* rrow = embb + (size_t)row * DE;
            for (int t = 0; t < DE; ++t) s = fmaf(b2f(rrow[t]), b2f(crow[t]), s);
            float d2c = fmaxf(fmaf(-2.0f, s, sqiv + sq[cr]), 1e-12f);
            bool tk = (d2c > kv) || (d2c == kv && cr < ki);
            kv = tk ? d2c : kv; ki = tk ? cr : ki;
        }
        for (int mm = 1; mm < 64; mm <<= 1) {
            float ov = __shfl_xor(kv, mm); int oi = __shfl_xor(ki, mm);
            bool tk = (ov > kv) || (ov == kv && oi < ki);
            kv = tk ? ov : kv; ki = tk ? oi : ki;
        }
        a2v = sqrtf(kv) - BIGF;
        j2 = ki;
    }

    // alpha dots + norms over clot
    const float4* c4 = (const float4*)clot;
    float s1 = 0.f, s2 = 0.f, n0 = 0.f, n1 = 0.f, n2 = 0.f;
    for (int t = lane; t < DC / 4; t += 64) {
        float4 a = c4[(size_t)row * (DC / 4) + t];
        float4 b1 = c4[(size_t)j1 * (DC / 4) + t];
        float4 b2 = c4[(size_t)j2 * (DC / 4) + t];
        s1 += a.x * b1.x + a.y * b1.y + a.z * b1.z + a.w * b1.w;
        s2 += a.x * b2.x + a.y * b2.y + a.z * b2.z + a.w * b2.w;
        n0 += a.x * a.x + a.y * a.y + a.z * a.z + a.w * a.w;
        n1 += b1.x * b1.x + b1.y * b1.y + b1.z * b1.z + b1.w * b1.w;
        n2 += b2.x * b2.x + b2.y * b2.y + b2.z * b2.z + b2.w * b2.w;
    }
    for (int mm = 1; mm < 64; mm <<= 1) {
        s1 += __shfl_xor(s1, mm); s2 += __shfl_xor(s2, mm);
        n0 += __shfl_xor(n0, mm); n1 += __shfl_xor(n1, mm); n2 += __shfl_xor(n2, mm);
    }
    if (lane == 0) {
        ap1[row] = a1; ap2[row] = a2v;
        an[row] = sqrtf(__uint_as_float(mnA[row]));
        alpha1[row] = s1 / (sqrtf(n0) * sqrtf(n1));
        alpha2[row] = s2 / (sqrtf(n0) * sqrtf(n2));
    }

    // ---- fused final reduction: last block to arrive does k_final's job ----
    __shared__ int isLast;
    __threadfence();                      // release: this block's writes visible device-wide
    __syncthreads();                      // all waves' writes + fences done
    if (threadIdx.x == 0) {
        int n = atomicAdd(ctr, 1);
        isLast = (n == (int)gridDim.x - 1);
    }
    __syncthreads();
    if (isLast) {
        __threadfence();                  // acquire: see all other blocks' writes
        int tid = threadIdx.x;
        float sl11 = 0.f, sl13 = 0.f, sp = 0.f;
        for (int rw = tid; rw < NR; rw += 256) {
            float a1f = alpha1[rw], a2f = alpha2[rw];
            float dap1 = ap1[rw], dap2 = ap2[rw], dan = an[rw];
            float y = (a1f < a2f) ? -1.f : 1.f;
            float ym = (a1f == a2f) ? 0.f : 1.f;
            float x1 = dap2 * ym;
            float x2 = dap1 * ym + MARG * (a1f - a2f - y);
            sl11 += fmaxf(0.f, -y * (x1 - x2) + MARG);
            float ap1m = dap1 + MARG * (a1f - 1.f);
            sl13 += fmaxf(0.f, -(dan - ap1m) + MARG);
            sp += (dan > ap1m) ? 1.f : 0.f;
        }
        for (int m = 1; m < 64; m <<= 1) {
            sl11 += __shfl_xor(sl11, m);
            sl13 += __shfl_xor(sl13, m);
            sp += __shfl_xor(sp, m);
        }
        __shared__ float r11[4], r13[4], rp[4];
        if ((tid & 63) == 0) { r11[tid >> 6] = sl11; r13[tid >> 6] = sl13; rp[tid >> 6] = sp; }
        __syncthreads();
        if (tid == 0) {
            float t11 = r11[0] + r11[1] + r11[2] + r11[3];
            float t13 = r13[0] + r13[1] + r13[2] + r13[3];
            float tp = rp[0] + rp[1] + rp[2] + rp[3];
            out[0] = 0.1f * (t11 / (float)NR) + t13 / (float)NR;
            out[1] = tp / (float)NR;
        }
    }
}

extern "C" void kernel_launch(void* const* d_in, const int* in_sizes, int n_in,
                              void* d_out, int out_size, void* d_ws, size_t ws_size,
                              hipStream_t stream) {
    const float* emb = (const float*)d_in[0];
    const int* label = (const int*)d_in[1];
    const float* clot = (const float*)d_in[2];
    float* out = (float*)d_out;

    char* ws = (char*)d_ws;
    size_t off = 0;
    auto alloc = [&](size_t bytes) -> char* {
        char* p = ws + off;
        off = (off + bytes + 255) & ~(size_t)255;
        return p;
    };
    short*    embb = (short*)alloc((size_t)NR * DE * 2);
    float*    pmat = (float*)alloc((size_t)512 * CAP * CAP * 4);   // 8MB per-class Gram
    float*    sq   = (float*)alloc(NR * 4);
    int*      cnt  = (int*)alloc(512 * 4);    // cnt, fill, ctr contiguous: ONE memset covers all
    int*      fill = (int*)alloc(512 * 4);
    int*      ctr  = (int*)alloc(256);
    int*      cOff = (int*)alloc(512 * 4);
    int*      list = (int*)alloc(NR * 4);
    int*      mIdx = (int*)alloc(NR * 4);
    unsigned* mnA  = (unsigned*)alloc((size_t)NR * 4);
    float*    ap1  = (float*)alloc(NR * 4);
    float*    ap2  = (float*)alloc(NR * 4);
    float*    an   = (float*)alloc(NR * 4);
    float*    al1  = (float*)alloc(NR * 4);
    float*    al2  = (float*)alloc(NR * 4);

    hipMemsetAsync(cnt, 0, 2 * 512 * 4 + 256, stream);     // cnt + fill + ctr in one node

    k_prep_emb<<<dim3(NR / 4), dim3(256), 0, stream>>>(emb, label, embb, sq, cnt, mnA);
    k_fill<<<dim3(NR / 256), dim3(256), 0, stream>>>(cnt, label, cOff, fill, list, mIdx);
    k_main<<<dim3(2080), dim3(256), 0, stream>>>(embb, sq, label, mIdx, mnA, pmat);
    k_pos<<<dim3(NR / 4), dim3(256), 0, stream>>>(embb, sq, clot, label, cnt, cOff, list,
                                                  mIdx, pmat, mnA, ap1, ap2, an, al1, al2,
                                                  ctr, out);
}

// Round 15
// 212.046 us; speedup vs baseline: 1.7899x; 1.7899x over previous
//
#include <hip/hip_runtime.h>
#include <stdint.h>

#define NR 8192
#define DE 1024
#define DC 512
#define BIGF 9999999.0f
#define MARG 0.3f
#define NEGI -3.0e38f
#define POSI 3.0e38f
#define CAP 64   // max class size served by posmat fast path; larger falls back (never for this input)

typedef __attribute__((ext_vector_type(8))) short bf16x8;
typedef __attribute__((ext_vector_type(4))) float f32x4;

typedef __attribute__((address_space(3))) unsigned int lds_u32;
typedef const __attribute__((address_space(1))) unsigned int glb_u32;

static __device__ __forceinline__ void ld_g2l16(const void* g, void* l) {
    __builtin_amdgcn_global_load_lds((glb_u32*)g, (lds_u32*)l, 16, 0, 0);
}

static __device__ __forceinline__ unsigned short f2bf(float x) {
    unsigned u = __float_as_uint(x);
    unsigned r = u + 0x7FFFu + ((u >> 16) & 1u);
    return (unsigned short)(r >> 16);
}

static __device__ __forceinline__ float b2f(short u) {
    return __uint_as_float(((unsigned)(unsigned short)u) << 16);
}

// ---------------- K1: emb -> bf16, sq, class histogram, mnA init ----------------
__global__ __launch_bounds__(256) void k_prep_emb(const float* __restrict__ emb,
                                                  const int* __restrict__ label,
                                                  short* __restrict__ embb,
                                                  float* __restrict__ sq,
                                                  int* __restrict__ cnt,
                                                  unsigned* __restrict__ mnA) {
    int w = threadIdx.x >> 6, lane = threadIdx.x & 63;
    int row = blockIdx.x * 4 + w;
    const float4* src = (const float4*)(emb + (size_t)row * DE);
    ushort4* dst = (ushort4*)(embb + (size_t)row * DE);
    float s = 0.f;
#pragma unroll
    for (int c = 0; c < 4; ++c) {
        float4 v = src[c * 64 + lane];
        s += v.x * v.x + v.y * v.y + v.z * v.z + v.w * v.w;
        ushort4 b;
        b.x = f2bf(v.x); b.y = f2bf(v.y); b.z = f2bf(v.z); b.w = f2bf(v.w);
        dst[c * 64 + lane] = b;
    }
    for (int m = 1; m < 64; m <<= 1) s += __shfl_xor(s, m);
    if (lane == 0) {
        sq[row] = s;
        atomicAdd(&cnt[label[row]], 1);
        mnA[row] = 0xFFFFFFFFu;          // +inf bits for positive-float atomicMin
    }
}

// ---------------- K3: scan (in-block, redundant) + scatter rows into class lists ----------------
__global__ __launch_bounds__(256) void k_fill(const int* __restrict__ cnt,
                                              const int* __restrict__ label,
                                              int* __restrict__ clsOff,
                                              int* __restrict__ fill,
                                              int* __restrict__ list,
                                              int* __restrict__ mIdx) {
    __shared__ int s[512];
    int t = threadIdx.x;
    s[t] = cnt[t];
    s[t + 256] = cnt[t + 256];
    __syncthreads();
    for (int d = 1; d < 512; d <<= 1) {
        int v0 = (t >= d) ? s[t - d] : 0;
        int v1 = s[t + 256 - d];
        __syncthreads();
        s[t] += v0;
        s[t + 256] += v1;
        __syncthreads();
    }
    if (blockIdx.x == 0) {
        clsOff[t] = s[t] - cnt[t];
        clsOff[t + 256] = s[t + 256] - cnt[t + 256];
    }
    int i = blockIdx.x * 256 + t;
    int l = label[i];
    int p = atomicAdd(&fill[l], 1);
    list[s[l] - cnt[l] + p] = i;
    mIdx[i] = p;
}

// ---------------- K4: symmetric GEMM + min-negative reduction + same-class d2 export ----------------
// R10 winner loop unchanged. mIdx preloaded into registers (mIj[4] with the column loads,
// mIi[4] with each mi-group's row loads) so the rare lbi==lbj branch body is compare +
// 2 fire-and-forget stores -- no dependent L2 loads in the divergent excursion.
// (R14's fused-final experiment is reverted; this epilogue change is measured in isolation
// this round vs R13's 108.9us.)
__global__ __launch_bounds__(256, 3) void k_main(const short* __restrict__ embb,
                                                 const float* __restrict__ sq,
                                                 const int* __restrict__ label,
                                                 const int* __restrict__ mIdx,
                                                 unsigned* __restrict__ mnA,
                                                 float* __restrict__ posmat) {
    // decode b -> (r, c), r <= c < 64: off(r) = 64r - r(r-1)/2 ; c = r + (b - off(r))
    const int b = blockIdx.x;
    int r = (int)((129.0f - sqrtf(16641.0f - 8.0f * (float)b)) * 0.5f);
    if (r < 0) r = 0;
    if (r > 63) r = 63;
    while (r > 0 && 64 * r - (r * (r - 1)) / 2 > b) --r;
    while (64 * (r + 1) - ((r + 1) * r) / 2 <= b) ++r;
    const int c = r + (b - (64 * r - (r * (r - 1)) / 2));
    const int i0 = r * 128, j0 = c * 128;

    __shared__ __align__(16) short As[128 * 64];   // 16KB
    __shared__ __align__(16) short Bs[128 * 64];   // 16KB

    const int tid = threadIdx.x;
    const int lane = tid & 63;
    const int w = tid >> 6;
    const int wr = w >> 1, wc = w & 1;       // 2x2 wave grid over the 128x128 panel
    const int q = lane >> 4, l15 = lane & 15;

    // staging source: row offset t>>3, source chunk g = slot ^ (row&7)
    const int g = (tid & 7) ^ ((tid >> 3) & 7);
    const short* gA = embb + (size_t)(i0 + (tid >> 3)) * DE + g * 8;
    const short* gB = embb + (size_t)(j0 + (tid >> 3)) * DE + g * 8;

    const int swz = l15 & 7;                 // read-side row swizzle key

    auto stage = [&](int koff) {
#pragma unroll
        for (int n = 0; n < 4; ++n) {
            ld_g2l16(gA + (size_t)n * 32 * DE + koff, &As[n * 2048 + tid * 8]);
            ld_g2l16(gB + (size_t)n * 32 * DE + koff, &Bs[n * 2048 + tid * 8]);
        }
    };

    stage(0);   // prefetch ks=0

    f32x4 acc[4][4];
#pragma unroll
    for (int mi = 0; mi < 4; ++mi)
#pragma unroll
        for (int ni = 0; ni < 4; ++ni) acc[mi][ni] = (f32x4){0.f, 0.f, 0.f, 0.f};

    for (int ks = 0; ks < 16; ++ks) {
        __syncthreads();          // staging visible (vmcnt drain)
        bf16x8 af[2][4], bfr[2][4];
#pragma unroll
        for (int kk = 0; kk < 2; ++kk) {
            const int kc = ((kk * 4 + q) ^ swz) * 8;
#pragma unroll
            for (int mi = 0; mi < 4; ++mi)
                af[kk][mi] = *(const bf16x8*)&As[(wr * 64 + mi * 16 + l15) * 64 + kc];
#pragma unroll
            for (int ni = 0; ni < 4; ++ni)
                bfr[kk][ni] = *(const bf16x8*)&Bs[(wc * 64 + ni * 16 + l15) * 64 + kc];
        }
#pragma unroll
        for (int kk = 0; kk < 2; ++kk)
#pragma unroll
            for (int mi = 0; mi < 4; ++mi)
#pragma unroll
                for (int ni = 0; ni < 4; ++ni)
                    acc[mi][ni] = __builtin_amdgcn_mfma_f32_16x16x32_bf16(af[kk][mi], bfr[kk][ni], acc[mi][ni], 0, 0, 0);
        __syncthreads();          // all reads done before next staging writes
        if (ks < 15) stage((ks + 1) * 64);
    }

    // ---- epilogue: masked d2 -> row/col min + same-class d2 -> posmat ----
    const int rb = i0 + wr * 64, cb = j0 + wc * 64;
    float sqj[4]; int lbj[4], mIj[4]; float cmn[4];
#pragma unroll
    for (int ni = 0; ni < 4; ++ni) {
        int cg = cb + ni * 16 + l15;
        sqj[ni] = sq[cg]; lbj[ni] = label[cg]; mIj[ni] = mIdx[cg]; cmn[ni] = POSI;
    }
#pragma unroll
    for (int mi = 0; mi < 4; ++mi) {
        float rm[4] = {POSI, POSI, POSI, POSI};
        float sqi[4]; int lbi[4], mIi[4];
#pragma unroll
        for (int rr = 0; rr < 4; ++rr) {
            int rg = rb + mi * 16 + q * 4 + rr;
            sqi[rr] = sq[rg]; lbi[rr] = label[rg]; mIi[rr] = mIdx[rg];
        }
#pragma unroll
        for (int ni = 0; ni < 4; ++ni)
#pragma unroll
            for (int rr = 0; rr < 4; ++rr) {
                float d2 = fmaf(-2.0f, acc[mi][ni][rr], sqi[rr] + sqj[ni]);
                d2 = fmaxf(d2, 1e-12f);
                if (lbi[rr] == lbj[ni]) {
                    int a = mIi[rr], bb = mIj[ni];
                    if (a < CAP && bb < CAP) {
                        float* pm = posmat + (size_t)lbi[rr] * CAP * CAP;
                        pm[a * CAP + bb] = d2;
                        pm[bb * CAP + a] = d2;
                    }
                }
                float dn = (lbi[rr] == lbj[ni]) ? POSI : d2;
                rm[rr] = fminf(rm[rr], dn);
                cmn[ni] = fminf(cmn[ni], dn);
            }
#pragma unroll
        for (int rr = 0; rr < 4; ++rr) {
            float v = rm[rr];
            v = fminf(v, __shfl_xor(v, 1));
            v = fminf(v, __shfl_xor(v, 2));
            v = fminf(v, __shfl_xor(v, 4));
            v = fminf(v, __shfl_xor(v, 8));
            if (l15 == 0) atomicMin(&mnA[rb + mi * 16 + q * 4 + rr], __float_as_uint(v));
        }
    }
#pragma unroll
    for (int ni = 0; ni < 4; ++ni) {
        float v = cmn[ni];
        v = fminf(v, __shfl_xor(v, 16));
        v = fminf(v, __shfl_xor(v, 32));
        if (q == 0) atomicMin(&mnA[cb + ni * 16 + l15], __float_as_uint(v));
    }
}

// ---------------- K5: positives (top-2) from posmat + alphas -- wave per row ----------------
// ROUND-15: fused-final REVERTED (R14: every block's device-scope __threadfence = L2
// writeback across non-coherent XCDs -> 2048 serialized flushes, k_pos 10->196us).
// Kernel boundary provides the coherence for free; k_final is its own node again.
__global__ __launch_bounds__(256) void k_pos(const short* __restrict__ embb,
                                             const float* __restrict__ sq,
                                             const float* __restrict__ clot,
                                             const int* __restrict__ label,
                                             const int* __restrict__ cnt,
                                             const int* __restrict__ clsOff,
                                             const int* __restrict__ clsList,
                                             const int* __restrict__ mIdx,
                                             const float* __restrict__ posmat,
                                             const unsigned* __restrict__ mnA,
                                             float* __restrict__ ap1, float* __restrict__ ap2,
                                             float* __restrict__ an,
                                             float* __restrict__ alpha1, float* __restrict__ alpha2) {
    int wid = threadIdx.x >> 6, lane = threadIdx.x & 63;
    int row = blockIdx.x * 4 + wid;
    int lb = label[row];
    int cc = cnt[lb], off = clsOff[lb];
    float sqiv = sq[row];

    float v1 = NEGI, v2 = NEGI;
    int i1 = 0, i2 = 0;
    auto upd = [&](float d2, int j) {
        bool t1 = (d2 > v1) || (d2 == v1 && j < i1);
        bool t2 = (d2 > v2) || (d2 == v2 && j < i2);
        v2 = t1 ? v1 : (t2 ? d2 : v2);
        i2 = t1 ? i1 : (t2 ? j : i2);
        v1 = t1 ? d2 : v1;
        i1 = t1 ? j : i1;
    };

    if (cc <= CAP) {
        const int self = mIdx[row];
        if (lane < cc) {
            float d2 = (lane == self) ? 1e-12f
                                      : posmat[((size_t)lb * CAP + self) * CAP + lane];
            upd(d2, clsList[off + lane]);
        }
        for (int d = 1; d < 64; d <<= 1) {
            float o1 = __shfl_xor(v1, d), o2 = __shfl_xor(v2, d);
            int oi1 = __shfl_xor(i1, d), oi2 = __shfl_xor(i2, d);
            upd(o1, oi1);
            upd(o2, oi2);
        }
    } else {
        // fallback: serial classmate dots (wave-parallel over D) -- never for this input
        const bf16x8* rp = (const bf16x8*)(embb + (size_t)row * DE + lane * 16);
        bf16x8 ra = rp[0], rb = rp[1];
        float rf[16];
#pragma unroll
        for (int t = 0; t < 8; ++t) { rf[t] = b2f(ra[t]); rf[8 + t] = b2f(rb[t]); }
        for (int m = 0; m < cc; ++m) {
            int j = clsList[off + m];
            float d2;
            if (j == row) {
                d2 = 1e-12f;
            } else {
                const bf16x8* jp = (const bf16x8*)(embb + (size_t)j * DE + lane * 16);
                bf16x8 ja = jp[0], jb = jp[1];
                float s = 0.f;
#pragma unroll
                for (int t = 0; t < 8; ++t) s = fmaf(rf[t], b2f(ja[t]), s);
#pragma unroll
                for (int t = 0; t < 8; ++t) s = fmaf(rf[8 + t], b2f(jb[t]), s);
                for (int mm = 1; mm < 64; mm <<= 1) s += __shfl_xor(s, mm);
                d2 = fmaxf(fmaf(-2.0f, s, sqiv + sq[j]), 1e-12f);
            }
            upd(d2, j);
        }
    }

    float a1 = sqrtf(v1);
    int j1 = i1;
    float a2v; int j2;
    if (cc >= 2) {
        a2v = sqrtf(v2);
        j2 = i2;
    } else {
        // singleton class: ref falls back to best (max-dist) negative - BIG
        float kv = NEGI; int ki = 0;
        for (int cr = lane; cr < NR; cr += 64) {
            if (label[cr] == lb) continue;
            float s = 0.f;
            const short* crow = embb + (size_t)cr * DE;
            const short* rrow = embb + (size_t)row * DE;
            for (int t = 0; t < DE; ++t) s = fmaf(b2f(rrow[t]), b2f(crow[t]), s);
            float d2c = fmaxf(fmaf(-2.0f, s, sqiv + sq[cr]), 1e-12f);
            bool tk = (d2c > kv) || (d2c == kv && cr < ki);
            kv = tk ? d2c : kv; ki = tk ? cr : ki;
        }
        for (int mm = 1; mm < 64; mm <<= 1) {
            float ov = __shfl_xor(kv, mm); int oi = __shfl_xor(ki, mm);
            bool tk = (ov > kv) || (ov == kv && oi < ki);
            kv = tk ? ov : kv; ki = tk ? oi : ki;
        }
        a2v = sqrtf(kv) - BIGF;
        j2 = ki;
    }

    // alpha dots + norms over clot
    const float4* c4 = (const float4*)clot;
    float s1 = 0.f, s2 = 0.f, n0 = 0.f, n1 = 0.f, n2 = 0.f;
    for (int t = lane; t < DC / 4; t += 64) {
        float4 a = c4[(size_t)row * (DC / 4) + t];
        float4 b1 = c4[(size_t)j1 * (DC / 4) + t];
        float4 b2 = c4[(size_t)j2 * (DC / 4) + t];
        s1 += a.x * b1.x + a.y * b1.y + a.z * b1.z + a.w * b1.w;
        s2 += a.x * b2.x + a.y * b2.y + a.z * b2.z + a.w * b2.w;
        n0 += a.x * a.x + a.y * a.y + a.z * a.z + a.w * a.w;
        n1 += b1.x * b1.x + b1.y * b1.y + b1.z * b1.z + b1.w * b1.w;
        n2 += b2.x * b2.x + b2.y * b2.y + b2.z * b2.z + b2.w * b2.w;
    }
    for (int mm = 1; mm < 64; mm <<= 1) {
        s1 += __shfl_xor(s1, mm); s2 += __shfl_xor(s2, mm);
        n0 += __shfl_xor(n0, mm); n1 += __shfl_xor(n1, mm); n2 += __shfl_xor(n2, mm);
    }
    if (lane == 0) {
        ap1[row] = a1; ap2[row] = a2v;
        an[row] = sqrtf(__uint_as_float(mnA[row]));
        alpha1[row] = s1 / (sqrtf(n0) * sqrtf(n1));
        alpha2[row] = s2 / (sqrtf(n0) * sqrtf(n2));
    }
}

// ---------------- K7: final loss + prec ----------------
__global__ __launch_bounds__(256) void k_final(const float* __restrict__ ap1, const float* __restrict__ ap2,
                                               const float* __restrict__ an,
                                               const float* __restrict__ alpha1, const float* __restrict__ alpha2,
                                               float* __restrict__ out) {
    int tid = threadIdx.x;
    float sl11 = 0.f, sl13 = 0.f, sp = 0.f;
    for (int row = tid; row < NR; row += 256) {
        float a1 = alpha1[row], a2 = alpha2[row];
        float dap1 = ap1[row], dap2 = ap2[row], dan = an[row];
        float y = (a1 < a2) ? -1.f : 1.f;
        float ym = (a1 == a2) ? 0.f : 1.f;
        float x1 = dap2 * ym;
        float x2 = dap1 * ym + MARG * (a1 - a2 - y);
        sl11 += fmaxf(0.f, -y * (x1 - x2) + MARG);
        float ap1m = dap1 + MARG * (a1 - 1.f);
        sl13 += fmaxf(0.f, -(dan - ap1m) + MARG);
        sp += (dan > ap1m) ? 1.f : 0.f;
    }
    for (int m = 1; m < 64; m <<= 1) {
        sl11 += __shfl_xor(sl11, m);
        sl13 += __shfl_xor(sl13, m);
        sp += __shfl_xor(sp, m);
    }
    __shared__ float r11[4], r13[4], rp[4];
    if ((tid & 63) == 0) { r11[tid >> 6] = sl11; r13[tid >> 6] = sl13; rp[tid >> 6] = sp; }
    __syncthreads();
    if (tid == 0) {
        float t11 = r11[0] + r11[1] + r11[2] + r11[3];
        float t13 = r13[0] + r13[1] + r13[2] + r13[3];
        float tp = rp[0] + rp[1] + rp[2] + rp[3];
        out[0] = 0.1f * (t11 / (float)NR) + t13 / (float)NR;
        out[1] = tp / (float)NR;
    }
}

extern "C" void kernel_launch(void* const* d_in, const int* in_sizes, int n_in,
                              void* d_out, int out_size, void* d_ws, size_t ws_size,
                              hipStream_t stream) {
    const float* emb = (const float*)d_in[0];
    const int* label = (const int*)d_in[1];
    const float* clot = (const float*)d_in[2];
    float* out = (float*)d_out;

    char* ws = (char*)d_ws;
    size_t off = 0;
    auto alloc = [&](size_t bytes) -> char* {
        char* p = ws + off;
        off = (off + bytes + 255) & ~(size_t)255;
        return p;
    };
    short*    embb = (short*)alloc((size_t)NR * DE * 2);
    float*    pmat = (float*)alloc((size_t)512 * CAP * CAP * 4);   // 8MB per-class Gram
    float*    sq   = (float*)alloc(NR * 4);
    int*      cnt  = (int*)alloc(512 * 4);    // cnt and fill contiguous: ONE memset covers both
    int*      fill = (int*)alloc(512 * 4);
    int*      cOff = (int*)alloc(512 * 4);
    int*      list = (int*)alloc(NR * 4);
    int*      mIdx = (int*)alloc(NR * 4);
    unsigned* mnA  = (unsigned*)alloc((size_t)NR * 4);
    float*    ap1  = (float*)alloc(NR * 4);
    float*    ap2  = (float*)alloc(NR * 4);
    float*    an   = (float*)alloc(NR * 4);
    float*    al1  = (float*)alloc(NR * 4);
    float*    al2  = (float*)alloc(NR * 4);

    hipMemsetAsync(cnt, 0, 2 * 512 * 4, stream);           // cnt + fill in one node

    k_prep_emb<<<dim3(NR / 4), dim3(256), 0, stream>>>(emb, label, embb, sq, cnt, mnA);
    k_fill<<<dim3(NR / 256), dim3(256), 0, stream>>>(cnt, label, cOff, fill, list, mIdx);
    k_main<<<dim3(2080), dim3(256), 0, stream>>>(embb, sq, label, mIdx, mnA, pmat);
    k_pos<<<dim3(NR / 4), dim3(256), 0, stream>>>(embb, sq, clot, label, cnt, cOff, list,
                                                  mIdx, pmat, mnA, ap1, ap2, an, al1, al2);
    k_final<<<dim3(1), dim3(256), 0, stream>>>(ap1, ap2, an, al1, al2, out);
}